// Round 12
// baseline (482.909 us; speedup 1.0000x reference)
//
#include <hip/hip_runtime.h>
#include <hip/hip_bf16.h>

// fastmax (degree-2 Taylor attention) for B=2,H=8,N=1024,D=64, fp32 in/out.
// o_i = sum_j (1 + s + 0.5 s^2) v_j / sum_j (1 + s + 0.5 s^2),
//   s_ij = q_i.k_j + q_i.rpe[i-j+N-1]
//
// Round 11 design (2nd submit; prior round was an infra GPU-acquisition
// timeout) = round-9 passing kernel (single-buffer staging; r10 dbuf reverted
// as neutral-negative) + ONE change: in-kernel last-block combine via
// device-scope atomic counter (reduce_kernel eliminated; counters zeroed by
// hipMemsetAsync on stream). Quarantined still: V^T swizzle, S-72,
// launch_bounds(,4).

#define NSEQ 1024
#define DH   64
#define BM   64
#define BN   64
#define NBH  16
#define ROWS_TOTAL (NBH * NSEQ)              // 16384
#define NUM_ELEMS  ((size_t)ROWS_TOTAL * DH) // 1,048,576

typedef short bf16x8 __attribute__((ext_vector_type(8)));
typedef float f32x4  __attribute__((ext_vector_type(4)));

__device__ __forceinline__ unsigned short f2bf(float x) {
    return __builtin_bit_cast(unsigned short, __float2bfloat16(x));
}
__device__ __forceinline__ unsigned pack2(float lo, float hi) {
    return (unsigned)f2bf(lo) | ((unsigned)f2bf(hi) << 16);
}
__device__ __forceinline__ unsigned long long pack4(float4 x) {
    unsigned lo = pack2(x.x, x.y), hi = pack2(x.z, x.w);
    return (unsigned long long)lo | ((unsigned long long)hi << 32);
}

template<int JSPLIT>
__global__ __launch_bounds__(512, 2)
void fastmax_kernel(const float* __restrict__ qg, const float* __restrict__ kg,
                    const float* __restrict__ vg, const float* __restrict__ rpe,
                    float* __restrict__ outg, float* __restrict__ wsbuf,
                    int* __restrict__ ctr)
{
    // K tile: 64 rows x 64 bf16, row stride 128B, XOR-swizzled
    __shared__ __align__(16) unsigned char ldsK[64 * 128];
    // RPE band: 128 rows x 64 bf16, swizzled
    __shared__ __align__(16) unsigned char ldsR[128 * 128];
    // V^T: [d=64][j=64] bf16, row stride 136B
    __shared__ __align__(16) unsigned char ldsVT[64 * 136];
    // per-wave score strip: 16 rows x 32 cols bf16, row stride 80B
    __shared__ __align__(16) unsigned char ldsS[8 * 16 * 80];
    __shared__ int s_last;

    const int tid = threadIdx.x;
    const int w   = tid >> 6;       // wave 0..7
    const int l   = tid & 63;
    const int lr  = l & 15;
    const int lg  = l >> 4;
    const int wst = w >> 1;         // row strip 0..3
    const int wj  = w & 1;          // j half 0..1

    const int b  = blockIdx.x;
    const int js = b % JSPLIT;
    const int it = (b / JSPLIT) & 15;
    const int bh = b / (JSPLIT * 16);
    const int i0 = it * BM;

    const float* qbh = qg + (size_t)bh * (NSEQ * DH);
    const float* kbh = kg + (size_t)bh * (NSEQ * DH);
    const float* vbh = vg + (size_t)bh * (NSEQ * DH);

    // Q A-fragments (A: m=lane&15, k=(lane>>4)*8+e)
    bf16x8 qf[2];
    {
        const float* qrow = qbh + (size_t)(i0 + wst * 16 + lr) * DH + lg * 8;
        #pragma unroll
        for (int kc = 0; kc < 2; ++kc) {
            float4 a  = *reinterpret_cast<const float4*>(qrow + kc * 32);
            float4 b4 = *reinterpret_cast<const float4*>(qrow + kc * 32 + 4);
            bf16x8 f;
            f[0] = (short)f2bf(a.x);  f[1] = (short)f2bf(a.y);
            f[2] = (short)f2bf(a.z);  f[3] = (short)f2bf(a.w);
            f[4] = (short)f2bf(b4.x); f[5] = (short)f2bf(b4.y);
            f[6] = (short)f2bf(b4.z); f[7] = (short)f2bf(b4.w);
            qf[kc] = f;
        }
    }

    f32x4 oacc[4];
    #pragma unroll
    for (int dt = 0; dt < 4; ++dt) oacc[dt] = (f32x4){0.f, 0.f, 0.f, 0.f};
    float dp[4] = {0.f, 0.f, 0.f, 0.f};

    unsigned char* myS = ldsS + w * (16 * 80);
    const int t0w = wst * 16 - wj * 32 + 32;   // base band index of wave's P strip

    constexpr int NJT = (NSEQ / BN) / JSPLIT;
    for (int jt = js * NJT; jt < (js + 1) * NJT; ++jt) {
        const int j0  = jt * BN;
        const int rlo = i0 - j0 + 960;        // always >= 0

        __syncthreads();

        { // stage K tile (64x64 fp32 -> bf16, swizzled)
            const float4* src = reinterpret_cast<const float4*>(kbh + (size_t)j0 * DH);
            #pragma unroll
            for (int itr = 0; itr < 2; ++itr) {
                int i = itr * 512 + tid;
                float4 x = src[i];
                int row = i >> 4, colb = (i & 15) * 8;
                *reinterpret_cast<unsigned long long*>(
                    ldsK + ((row * 128 + colb) ^ ((row & 7) << 4))) = pack4(x);
            }
        }
        { // stage RPE band (rows rlo..rlo+127; clamped row feeds only unused t=47)
            #pragma unroll
            for (int itr = 0; itr < 4; ++itr) {
                int i = itr * 512 + tid;
                int row = i >> 4;
                int r = rlo + row; if (r > 2 * NSEQ - 2) r = 2 * NSEQ - 2;
                float4 x = reinterpret_cast<const float4*>(rpe)[r * 16 + (i & 15)];
                int colb = (i & 15) * 8;
                *reinterpret_cast<unsigned long long*>(
                    ldsR + ((row * 128 + colb) ^ ((row & 7) << 4))) = pack4(x);
            }
        }
        { // stage V^T (transpose during store; scalar b16 writes)
            const float4* src = reinterpret_cast<const float4*>(vbh + (size_t)j0 * DH);
            #pragma unroll
            for (int itr = 0; itr < 2; ++itr) {
                int i = itr * 512 + tid;
                float4 x = src[i];
                int j = i >> 4, d0 = (i & 15) * 4;
                unsigned char* p = ldsVT + j * 2;
                *reinterpret_cast<unsigned short*>(p + (d0 + 0) * 136) = f2bf(x.x);
                *reinterpret_cast<unsigned short*>(p + (d0 + 1) * 136) = f2bf(x.y);
                *reinterpret_cast<unsigned short*>(p + (d0 + 2) * 136) = f2bf(x.z);
                *reinterpret_cast<unsigned short*>(p + (d0 + 3) * 136) = f2bf(x.w);
            }
        }
        __syncthreads();

        // ---- P strip (in regs): P[m][t] = q_m . rpe[rlo + t0w + t], t in [0,48)
        f32x4 pacc[3];
        #pragma unroll
        for (int ct = 0; ct < 3; ++ct) pacc[ct] = (f32x4){0.f, 0.f, 0.f, 0.f};
        #pragma unroll
        for (int kc = 0; kc < 2; ++kc) {
            #pragma unroll
            for (int ct = 0; ct < 3; ++ct) {
                int row = t0w + ct * 16 + lr;
                bf16x8 bfrag = *reinterpret_cast<const bf16x8*>(
                    ldsR + ((row * 128 + kc * 64 + lg * 16) ^ ((row & 7) << 4)));
                pacc[ct] = __builtin_amdgcn_mfma_f32_16x16x32_bf16(qf[kc], bfrag, pacc[ct], 0, 0, 0);
            }
        }

        // ---- QK^T strip: rows 16 (m), cols [wj*32, wj*32+32)
        f32x4 sacc[2];
        #pragma unroll
        for (int ct = 0; ct < 2; ++ct) sacc[ct] = (f32x4){0.f, 0.f, 0.f, 0.f};
        #pragma unroll
        for (int kc = 0; kc < 2; ++kc) {
            #pragma unroll
            for (int ct = 0; ct < 2; ++ct) {
                int row = wj * 32 + ct * 16 + lr;
                bf16x8 bfrag = *reinterpret_cast<const bf16x8*>(
                    ldsK + ((row * 128 + kc * 64 + lg * 16) ^ ((row & 7) << 4)));
                sacc[ct] = __builtin_amdgcn_mfma_f32_16x16x32_bf16(qf[kc], bfrag, sacc[ct], 0, 0, 0);
            }
        }

        // ---- gather Toeplitz P term via bpermute, score, write S (bf16)
        // Need P[m][t], t = 31 + m - (ct_s*16 + lr). P[m][t] = pacc[t>>4][m&3]
        // at lane (same lg group, lane (t&15) = (m-lr+15)&15).
        // ct_s=0 -> (m>lr ? pacc2 : pacc1); ct_s=1 -> (m>lr ? pacc1 : pacc0).
        #pragma unroll
        for (int r = 0; r < 4; ++r) {
            int m = lg * 4 + r;
            int idx = ((l & 48) + ((m - lr + 15) & 15)) << 2;
            int g0 = __builtin_amdgcn_ds_bpermute(idx, __float_as_int(pacc[0][r]));
            int g1 = __builtin_amdgcn_ds_bpermute(idx, __float_as_int(pacc[1][r]));
            int g2 = __builtin_amdgcn_ds_bpermute(idx, __float_as_int(pacc[2][r]));
            bool hi = (m > lr);
            float p0 = __int_as_float(hi ? g2 : g1);   // ct_s = 0
            float p1 = __int_as_float(hi ? g1 : g0);   // ct_s = 1
            float s0 = sacc[0][r] + p0;
            float c0 = fmaf(s0, fmaf(0.5f, s0, 1.0f), 1.0f);
            dp[r] += c0;
            *reinterpret_cast<unsigned short*>(myS + m * 80 + lr * 2) = f2bf(c0);
            float s1 = sacc[1][r] + p1;
            float c1 = fmaf(s1, fmaf(0.5f, s1, 1.0f), 1.0f);
            dp[r] += c1;
            *reinterpret_cast<unsigned short*>(myS + m * 80 + 32 + lr * 2) = f2bf(c1);
        }

        // ---- O += score(16x32) * V(32x64)
        bf16x8 af = *reinterpret_cast<const bf16x8*>(myS + lr * 80 + lg * 16);
        #pragma unroll
        for (int dt = 0; dt < 4; ++dt) {
            const unsigned char* vp = ldsVT + (dt * 16 + lr) * 136 + wj * 64 + lg * 16;
            union { unsigned long long u[2]; bf16x8 v; } bb;
            bb.u[0] = *reinterpret_cast<const unsigned long long*>(vp);
            bb.u[1] = *reinterpret_cast<const unsigned long long*>(vp + 8);
            oacc[dt] = __builtin_amdgcn_mfma_f32_16x16x32_bf16(af, bb.v, oacc[dt], 0, 0, 0);
        }
    }

    // ---- denom: reduce across the 16 lanes of each row group
    #pragma unroll
    for (int r = 0; r < 4; ++r) {
        #pragma unroll
        for (int m = 1; m < 16; m <<= 1) dp[r] += __shfl_xor(dp[r], m, 64);
    }

    if constexpr (JSPLIT == 1) {
        // combine the two j-half partials through LDS (reuse ldsR / ldsK)
        __syncthreads();
        float* ored = reinterpret_cast<float*>(ldsR);   // [strip][row][64] fp32
        float* dred = reinterpret_cast<float*>(ldsK);   // [strip][row] fp32
        if (wj == 1) {
            #pragma unroll
            for (int dt = 0; dt < 4; ++dt) {
                #pragma unroll
                for (int r = 0; r < 4; ++r) {
                    int row = lg * 4 + r;
                    ored[wst * 1024 + row * 64 + dt * 16 + lr] = oacc[dt][r];
                }
            }
            if (lr == 0) {
                #pragma unroll
                for (int r = 0; r < 4; ++r) dred[wst * 16 + lg * 4 + r] = dp[r];
            }
        }
        __syncthreads();
        if (wj == 0) {
            float* ob = outg + (size_t)bh * (NSEQ * DH) + (size_t)(i0 + wst * 16) * DH;
            float rd[4];
            #pragma unroll
            for (int r = 0; r < 4; ++r) {
                int row = lg * 4 + r;
                rd[r] = 1.0f / (dp[r] + dred[wst * 16 + row]);
            }
            #pragma unroll
            for (int dt = 0; dt < 4; ++dt) {
                #pragma unroll
                for (int r = 0; r < 4; ++r) {
                    int row = lg * 4 + r;
                    float num = oacc[dt][r] + ored[wst * 1024 + row * 64 + dt * 16 + lr];
                    ob[row * DH + dt * 16 + lr] = num * rd[r];
                }
            }
        }
    } else {
        // each wave writes its own partial (j-half + j-split => 2*JSPLIT partials)
        const int js2  = js * 2 + wj;                 // 0 .. 2*JSPLIT-1
        const int rowg = bh * NSEQ + i0 + wst * 16;   // global row of strip base
        float* nw = wsbuf + (size_t)js2 * NUM_ELEMS + (size_t)rowg * DH;
        #pragma unroll
        for (int dt = 0; dt < 4; ++dt) {
            #pragma unroll
            for (int r = 0; r < 4; ++r) {
                nw[(lg * 4 + r) * DH + dt * 16 + lr] = oacc[dt][r];
            }
        }
        float* dw = wsbuf + (size_t)(2 * JSPLIT) * NUM_ELEMS + (size_t)js2 * ROWS_TOTAL + rowg;
        if (lr == 0) {
            #pragma unroll
            for (int r = 0; r < 4; ++r) dw[lg * 4 + r] = dp[r];
        }

        // ---- last-block-per-group combine (replaces reduce_kernel)
        __threadfence();          // release this block's partial writes
        __syncthreads();
        if (tid == 0) {
            int grp = bh * 16 + it;
            int old = atomicAdd(ctr + grp, 1);
            s_last = (old == JSPLIT - 1);
        }
        __syncthreads();
        if (s_last) {
            __threadfence();      // acquire sibling blocks' writes
            const int   row  = tid >> 3;            // 0..63 tile-local row
            const int   c0   = (tid & 7) * 8;
            const int   rowg2 = bh * NSEQ + i0 + row;
            const float* dbase = wsbuf + (size_t)(2 * JSPLIT) * NUM_ELEMS;
            float acc0 = 0.f, acc1 = 0.f, acc2 = 0.f, acc3 = 0.f;
            float acc4 = 0.f, acc5 = 0.f, acc6 = 0.f, acc7 = 0.f;
            float den = 0.f;
            #pragma unroll
            for (int p = 0; p < 2 * JSPLIT; ++p) {
                const float* nwp = wsbuf + (size_t)p * NUM_ELEMS + (size_t)rowg2 * DH + c0;
                float4 a = *reinterpret_cast<const float4*>(nwp);
                float4 b4 = *reinterpret_cast<const float4*>(nwp + 4);
                acc0 += a.x;  acc1 += a.y;  acc2 += a.z;  acc3 += a.w;
                acc4 += b4.x; acc5 += b4.y; acc6 += b4.z; acc7 += b4.w;
                den += dbase[(size_t)p * ROWS_TOTAL + rowg2];
            }
            float rdi = 1.0f / den;
            float* ob = outg + (size_t)rowg2 * DH + c0;
            float4 o0 = make_float4(acc0 * rdi, acc1 * rdi, acc2 * rdi, acc3 * rdi);
            float4 o1 = make_float4(acc4 * rdi, acc5 * rdi, acc6 * rdi, acc7 * rdi);
            *reinterpret_cast<float4*>(ob)     = o0;
            *reinterpret_cast<float4*>(ob + 4) = o1;
        }
    }
}

extern "C" void kernel_launch(void* const* d_in, const int* in_sizes, int n_in,
                              void* d_out, int out_size, void* d_ws, size_t ws_size,
                              hipStream_t stream) {
    const float* q   = (const float*)d_in[0];
    const float* k   = (const float*)d_in[1];
    const float* v   = (const float*)d_in[2];
    // d_in[3] = drop_noise, unused (dropout = 0)
    const float* rpe = (const float*)d_in[4];
    float* out = (float*)d_out;
    float* wsb = (float*)d_ws;

    // ws layout (floats): [2J partial numerators][2J partial denoms][counters]
    auto needf = [](int jsplit) -> size_t {
        return (size_t)(2 * jsplit) * NUM_ELEMS + (size_t)(2 * jsplit) * ROWS_TOTAL;
    };
    auto need = [&](int jsplit) -> size_t {
        return needf(jsplit) * sizeof(float) + 256 * sizeof(int);
    };

    if (ws_size >= need(4)) {
        int* ctr = (int*)(wsb + needf(4));
        hipMemsetAsync(ctr, 0, 256 * sizeof(int), stream);
        hipLaunchKernelGGL((fastmax_kernel<4>), dim3(256 * 4), dim3(512), 0, stream,
                           q, k, v, rpe, out, wsb, ctr);
    } else if (ws_size >= need(2)) {
        int* ctr = (int*)(wsb + needf(2));
        hipMemsetAsync(ctr, 0, 256 * sizeof(int), stream);
        hipLaunchKernelGGL((fastmax_kernel<2>), dim3(256 * 2), dim3(512), 0, stream,
                           q, k, v, rpe, out, wsb, ctr);
    } else {
        hipLaunchKernelGGL((fastmax_kernel<1>), dim3(256), dim3(512), 0, stream,
                           q, k, v, rpe, out, wsb, (int*)wsb);
    }
}